// Round 11
// baseline (133.465 us; speedup 1.0000x reference)
//
#include <hip/hip_runtime.h>

typedef __fp16 f16x2 __attribute__((ext_vector_type(2)));

#define Dm 128
#define Bn 16
#define VOX (Dm * Dm * Dm)
#define NT 256
#define WR 19            // words per halo row (ODD -> all 32 banks, ~2-way)
#define SLAB 589         // 31 rows x 19 words (30 data rows: 3z x 10y)
#define NSL 9            // staging slots/thread (9*64=576 >= 570)

__device__ __forceinline__ int iclamp(int v, int lo, int hi) {
  return v < lo ? lo : (v > hi ? hi : v);
}
__device__ __forceinline__ f16x2 pkrtz(float lo, float hi) {
  return __builtin_amdgcn_cvt_pkrtz(lo, hi);
}
__device__ __forceinline__ float pkbits(float lo, float hi) {
  return __builtin_bit_cast(float, __builtin_amdgcn_cvt_pkrtz(lo, hi));
}
__device__ __forceinline__ f16x2 asf16x2(float w) {
  return __builtin_bit_cast(f16x2, w);
}
// midpair(P, Q) = (Q.hi, P.lo)
__device__ __forceinline__ f16x2 midpair(f16x2 P, f16x2 Q) {
  unsigned r = __builtin_amdgcn_perm(__builtin_bit_cast(unsigned, P),
                                     __builtin_bit_cast(unsigned, Q),
                                     0x05040302u);
  return __builtin_bit_cast(f16x2, r);
}

// W transposed (wpkT[t*27+o] = W[o][t]) + bias, duplicated-half f16x2.
extern "C" __global__ void packW(const float* __restrict__ Wf,
                                 const float* __restrict__ bfp,
                                 float* __restrict__ wpk) {
  int i = threadIdx.x;
  if (i < 729) {
    int o = i / 27, t = i - o * 27;
    float v = Wf[i];
    wpk[t * 27 + o] = pkbits(v, v);
  } else if (i < 756) {
    float b = bfp[i - 729];
    wpk[i] = pkbits(b, b);
  }
}

__device__ __forceinline__ void load_batch(float2 nx[NSL], const float* xb,
                                           const int off[NSL]) {
#pragma unroll
  for (int k = 0; k < NSL; ++k) nx[k] = *(const float2*)(xb + off[k]);
}
__device__ __forceinline__ void stage_lds(float* sxw, const float2 nx[NSL],
                                          int lane) {
#pragma unroll
  for (int k = 0; k < NSL; ++k)
    sxw[64 * k + lane] = pkbits(nx[k].x, nx[k].y);
}

// 4 voxels/thread apply: per rr read u0..u3 (2x ds_read2_b32), 3 perms, 6 pk_fma.
__device__ __forceinline__ void apply_tile4(const float* sxw,
                                            const f16x2* KA, const f16x2* KB,
                                            int ty, int tx,
                                            f16x2& outA, f16x2& outB) {
  f16x2 aAa = {(__fp16)0.f, (__fp16)0.f}, aAb = aAa;
  f16x2 aBa = aAa, aBb = aAa;
#pragma unroll
  for (int rr = 0; rr < 9; ++rr) {
    const int idx = ((rr / 3) * 10 + ty + (rr % 3)) * WR + 2 * tx;
    float u0 = sxw[idx], u1 = sxw[idx + 1], u2 = sxw[idx + 2], u3 = sxw[idx + 3];
    f16x2 h1 = asf16x2(u1), h2 = asf16x2(u2);
    f16x2 m01 = midpair(h1, asf16x2(u0));   // (w-1, w)
    f16x2 m12 = midpair(h2, h1);            // (w+1, w+2)
    f16x2 m23 = midpair(asf16x2(u3), h2);   // (w+3, w+4)
    if (rr & 1) {
      aAb = __builtin_elementwise_fma(KA[rr * 3 + 0], m01, aAb);
      aAb = __builtin_elementwise_fma(KA[rr * 3 + 1], h1,  aAb);
      aAb = __builtin_elementwise_fma(KA[rr * 3 + 2], m12, aAb);
      aBb = __builtin_elementwise_fma(KB[rr * 3 + 0], m12, aBb);
      aBb = __builtin_elementwise_fma(KB[rr * 3 + 1], h2,  aBb);
      aBb = __builtin_elementwise_fma(KB[rr * 3 + 2], m23, aBb);
    } else {
      aAa = __builtin_elementwise_fma(KA[rr * 3 + 0], m01, aAa);
      aAa = __builtin_elementwise_fma(KA[rr * 3 + 1], h1,  aAa);
      aAa = __builtin_elementwise_fma(KA[rr * 3 + 2], m12, aAa);
      aBa = __builtin_elementwise_fma(KB[rr * 3 + 0], m12, aBa);
      aBa = __builtin_elementwise_fma(KB[rr * 3 + 1], h2,  aBa);
      aBa = __builtin_elementwise_fma(KB[rr * 3 + 2], m23, aBa);
    }
  }
  outA = aAa + aAb;
  outB = aBa + aBb;
}

// Wave-private z-slice tiles (8y x 32w voxels, 4/thread), zero barriers.
extern "C" __global__ void __launch_bounds__(NT, 4)
fused3d(const float* __restrict__ img, const float* __restrict__ x,
        const float* __restrict__ wpk, float* __restrict__ out)
{
  __shared__ float sX0[4][SLAB];    // 9.4 KiB (img during K-gen, then even b)
  __shared__ float sX1[4][SLAB];    // 9.4 KiB (odd b)

  const int tid  = threadIdx.x;
  const int lane = tid & 63;
  const int wv   = tid >> 6;       // wave id == z offset within block tile
  const int tx   = lane & 7;       // w-quad 0..7 (voxels 4tx..4tx+3)
  const int ty   = lane >> 3;      // h 0..7

  // T1 XCD swizzle: contiguous slab of 256 tiles per XCD
  const int bid = blockIdx.x;                 // 0..2047
  const int s  = (bid & 7) * 256 + (bid >> 3);
  const int bx = s & 3, by = (s >> 2) & 15, bz = s >> 6;
  const int w0 = bx * 32, h0 = by * 8, d0 = bz * 4;

  // ---- staging map: word i = 64k+lane -> r=i/19 (zz=r/10,yy=r%10), c=i%19.
  // Word holds halves (w0-2+2c, w0-1+2c), clamped; r>=30 and c==18 are pad.
  int off[NSL];
  float mk0[NSL], mk1[NSL];        // img zero-pad masks (conv SAME)
#pragma unroll
  for (int k = 0; k < NSL; ++k) {
    int i  = 64 * k + lane;
    int r  = i / WR;
    int c  = i - r * WR;
    int zz = r / 10;
    int yy = r - zz * 10;
    int gdo = d0 + wv + zz - 1;
    int gho = h0 + yy - 1;
    int gwo = w0 - 2 + 2 * c;
    int gd = iclamp(gdo, 0, Dm - 1);
    int gh = iclamp(gho, 0, Dm - 1);
    int gw = iclamp(gwo, 0, Dm - 2);        // even bounds keep 8B alignment
    off[k] = (gd * Dm + gh) * Dm + gw;
    bool rk = ((unsigned)gdo < Dm) & ((unsigned)gho < Dm) & (zz < 3);
    mk0[k] = (rk & ((unsigned)gwo < Dm))       ? 1.f : 0.f;
    mk1[k] = (rk & ((unsigned)(gwo + 1) < Dm)) ? 1.f : 0.f;
  }

  float* sx0 = sX0[wv];
  float* sx1 = sX1[wv];

  // ---- issue batch-0 loads FIRST (K-gen covers latency), stage img -> sx0
  float2 nxA[NSL], nxB[NSL];
  load_batch(nxA, x, off);
#pragma unroll
  for (int k = 0; k < NSL; ++k) {
    float2 v = *(const float2*)(img + off[k]);
    sx0[64 * k + lane] = pkbits(v.x * mk0[k], v.y * mk1[k]);
  }

  // ---- K-gen for 4 voxels (KA: w,w+1; KB: w+2,w+3), packed fp16,
  // W rows contiguous via wpkT (wave-uniform s_loads).
  f16x2 KA[27], KB[27];
#pragma unroll
  for (int o = 0; o < 27; ++o) { KA[o] = asf16x2(wpk[729 + o]); KB[o] = KA[o]; }
#pragma unroll
  for (int rr = 0; rr < 9; ++rr) {
    const int idx = ((rr / 3) * 10 + ty + (rr % 3)) * WR + 2 * tx;
    float u0 = sx0[idx], u1 = sx0[idx + 1], u2 = sx0[idx + 2], u3 = sx0[idx + 3];
    f16x2 h1 = asf16x2(u1), h2 = asf16x2(u2);
    f16x2 m01 = midpair(h1, asf16x2(u0));
    f16x2 m12 = midpair(h2, h1);
    f16x2 m23 = midpair(asf16x2(u3), h2);
    const float* wA = wpk + (rr * 3 + 0) * 27;
    const float* wB = wpk + (rr * 3 + 1) * 27;
    const float* wC = wpk + (rr * 3 + 2) * 27;
#pragma unroll
    for (int o = 0; o < 27; ++o) {
      f16x2 wa = asf16x2(wA[o]), wb = asf16x2(wB[o]), wc = asf16x2(wC[o]);
      KA[o] = __builtin_elementwise_fma(wa, m01, KA[o]);
      KA[o] = __builtin_elementwise_fma(wb, h1,  KA[o]);
      KA[o] = __builtin_elementwise_fma(wc, m12, KA[o]);
      KB[o] = __builtin_elementwise_fma(wa, m12, KB[o]);
      KB[o] = __builtin_elementwise_fma(wb, h2,  KB[o]);
      KB[o] = __builtin_elementwise_fma(wc, m23, KB[o]);
    }
  }

  // ---- boundary tap masks (x zero-pad semantics; kills bias too)
  const int od = d0 + wv, oh = h0 + ty, ow = w0 + 4 * tx;
#pragma unroll
  for (int o = 0; o < 27; ++o) {
    const int di = o / 9, dj = (o / 3) % 3, dk = o % 3;
    const bool mm = ((unsigned)(od + di - 1) < Dm) & ((unsigned)(oh + dj - 1) < Dm);
    const float a0 = (mm & ((unsigned)(ow + dk - 1) < Dm)) ? 1.f : 0.f;
    const float a1 = (mm & ((unsigned)(ow + dk)     < Dm)) ? 1.f : 0.f;
    const float b0 = (mm & ((unsigned)(ow + dk + 1) < Dm)) ? 1.f : 0.f;
    const float b1 = (mm & ((unsigned)(ow + dk + 2) < Dm)) ? 1.f : 0.f;
    KA[o] *= pkrtz(a0, a1);
    KB[o] *= pkrtz(b0, b1);
  }

  const size_t obase = (((size_t)od) * Dm + oh) * Dm + ow;  // 16B aligned

  // ---- batch loop: unroll-by-2, static nxA/nxB + LDS dbuf, no barriers.
#pragma unroll 1
  for (int bb = 0; bb < Bn; bb += 2) {
    stage_lds(sx1, nxA, lane);
    load_batch(nxB, x + (size_t)(bb + 1) * VOX, off);
    {
      f16x2 oA, oB;
      apply_tile4(sx1, KA, KB, ty, tx, oA, oB);
      float4 st; st.x = (float)oA.x; st.y = (float)oA.y;
      st.z = (float)oB.x; st.w = (float)oB.y;
      *(float4*)&out[(size_t)bb * VOX + obase] = st;
    }
    stage_lds(sx0, nxB, lane);
    if (bb + 2 < Bn) load_batch(nxA, x + (size_t)(bb + 2) * VOX, off);
    {
      f16x2 oA, oB;
      apply_tile4(sx0, KA, KB, ty, tx, oA, oB);
      float4 st; st.x = (float)oA.x; st.y = (float)oA.y;
      st.z = (float)oB.x; st.w = (float)oB.y;
      *(float4*)&out[(size_t)(bb + 1) * VOX + obase] = st;
    }
  }
}

extern "C" void kernel_launch(void* const* d_in, const int* in_sizes, int n_in,
                              void* d_out, int out_size, void* d_ws, size_t ws_size,
                              hipStream_t stream) {
  const float* img = (const float*)d_in[0];
  const float* x   = (const float*)d_in[1];
  const float* Wf  = (const float*)d_in[2];
  const float* bf  = (const float*)d_in[3];
  float* out = (float*)d_out;
  float* wpk = (float*)d_ws;   // 756 floats: wpkT + bias, packed f16x2
  hipLaunchKernelGGL(packW, dim3(1), dim3(768), 0, stream, Wf, bf, wpk);
  // 2048 blocks: 4(w) x 16(h) x 32(z) tiles of 32w x 8y x 4z
  hipLaunchKernelGGL(fused3d, dim3(2048), dim3(NT), 0, stream, img, x, wpk, out);
}